// Round 1
// baseline (1333.530 us; speedup 1.0000x reference)
//
#include <hip/hip_runtime.h>
#include <math.h>

#define BB 8
#define CC 128
#define HH 256
#define WW 256
#define PLANE (HH * WW)

// ---------------------------------------------------------------------------
// Effective spatial kernel of irfft2(rfft2(y)*filt):  per-channel 8x8 circular
// conv kernel.  k_c[u,n] = (1/64) sum_{p,q} m_q filt[c,p,q] cos(2pi(pu+qn)/8),
// m_q = 1 for q in {0,4}, else 2 (Hermitian mirror; DC/Nyquist imag dropped,
// matching pocketfft c2r semantics).
// ---------------------------------------------------------------------------
__global__ __launch_bounds__(256) void make_k_kernel(
    const float* __restrict__ filt, float* __restrict__ kk) {
  int idx = blockIdx.x * 256 + threadIdx.x;
  if (idx >= CC * 64) return;
  int c = idx >> 6;
  int u = (idx >> 3) & 7;
  int n = idx & 7;
  const float cs8[8] = {1.f, 0.70710678118654752f, 0.f, -0.70710678118654752f,
                        -1.f, -0.70710678118654752f, 0.f, 0.70710678118654752f};
  float s = 0.f;
#pragma unroll
  for (int p = 0; p < 8; ++p) {
#pragma unroll
    for (int q = 0; q < 5; ++q) {
      float m = (q == 0 || q == 4) ? 1.f : 2.f;
      s += m * filt[(c * 8 + p) * 5 + q] * cs8[(p * u + q * n) & 7];
    }
  }
  kk[idx] = s * (1.f / 64.f);
}

// ---------------------------------------------------------------------------
// Fused: w_in mix -> per-channel 8x8 circular conv (register shuffles) ->
// exact GeGLU -> w_before mix.  One block per 8x8 patch.
// ---------------------------------------------------------------------------
__global__ __launch_bounds__(256) void fused1_kernel(
    const float* __restrict__ x, const float* __restrict__ w_in,
    const float* __restrict__ w_before, const float* __restrict__ kk,
    float* __restrict__ g2) {
  __shared__ float buf[128 * 64];  // x patch, later y2 (post-conv)
  __shared__ float gb[64 * 64];    // gated activations

  int bid = blockIdx.x;
  int b = bid >> 10;
  int py = (bid >> 5) & 31;
  int px = bid & 31;
  int h0 = py * 8, w0 = px * 8;
  int t = threadIdx.x;
  const float* xb = x + (size_t)b * CC * PLANE;

  // ---- load 128ch x 8x8 patch into LDS (float4 granules) ----
#pragma unroll
  for (int i = 0; i < 8; ++i) {
    int f = t + 256 * i;  // float4 id, 0..2047
    int r = f >> 1;       // c*8 + ph
    int k4 = f & 1;
    int c = r >> 3, ph = r & 7;
    float4 v = *(const float4*)(xb + (size_t)c * PLANE + (size_t)(h0 + ph) * WW +
                                w0 + k4 * 4);
    *(float4*)(buf + c * 64 + ph * 8 + k4 * 4) = v;
  }
  __syncthreads();

  int ob = t >> 3;  // 0..31: owns out-channels ob*4..ob*4+3
  int pb = t & 7;   // patch row u

  // ---- stage A: y[o][pb][:] = sum_c w_in[o,c] * x[c][pb][:] ----
  float acc[4][8];
#pragma unroll
  for (int i = 0; i < 4; ++i)
#pragma unroll
    for (int j = 0; j < 8; ++j) acc[i][j] = 0.f;

#pragma unroll 2
  for (int c = 0; c < 128; ++c) {
    float4 lo = *(const float4*)(buf + c * 64 + pb * 8);
    float4 hi = *(const float4*)(buf + c * 64 + pb * 8 + 4);
    float xv[8] = {lo.x, lo.y, lo.z, lo.w, hi.x, hi.y, hi.z, hi.w};
#pragma unroll
    for (int i = 0; i < 4; ++i) {
      float wv = w_in[(ob * 4 + i) * 128 + c];
#pragma unroll
      for (int j = 0; j < 8; ++j) acc[i][j] += wv * xv[j];
    }
  }

  // ---- stage B: 8x8 circular conv, rows fetched cross-lane via shfl ----
  // y2[u,v] = sum_{s,tt} k[s,tt] * y[(u-s)&7][(v-tt)&7]; u=pb, v=j.
  float acc2[4][8];
#pragma unroll
  for (int i = 0; i < 4; ++i)
#pragma unroll
    for (int j = 0; j < 8; ++j) acc2[i][j] = 0.f;

#pragma unroll
  for (int i = 0; i < 4; ++i) {
    int o = ob * 4 + i;
    const float* krow = kk + o * 64;
#pragma unroll
    for (int s = 0; s < 8; ++s) {
      float r8[8];
      if (s == 0) {
#pragma unroll
        for (int j = 0; j < 8; ++j) r8[j] = acc[i][j];
      } else {
        int src = (t & 56) | ((t - s) & 7);
#pragma unroll
        for (int j = 0; j < 8; ++j) r8[j] = __shfl(acc[i][j], src, 64);
      }
#pragma unroll
      for (int tt = 0; tt < 8; ++tt) {
        float kv = krow[s * 8 + tt];
#pragma unroll
        for (int j = 0; j < 8; ++j) acc2[i][j] += kv * r8[(j - tt) & 7];
      }
    }
  }
  __syncthreads();  // all waves done reading x patch from buf

  // ---- write y2 into buf ----
#pragma unroll
  for (int i = 0; i < 4; ++i) {
    float* dst = buf + (ob * 4 + i) * 64 + pb * 8;
    *(float4*)dst = make_float4(acc2[i][0], acc2[i][1], acc2[i][2], acc2[i][3]);
    *(float4*)(dst + 4) =
        make_float4(acc2[i][4], acc2[i][5], acc2[i][6], acc2[i][7]);
  }
  __syncthreads();

  // ---- stage C: g[c] = gelu_exact(y2[c]) * y2[c+64] ----
#pragma unroll
  for (int it = 0; it < 16; ++it) {
    int f = t + it * 256;  // c*64 + pix, c<64
    float a = buf[f];
    float g = buf[f + 4096];
    float ge = 0.5f * a * (1.f + erff(a * 0.70710678118654752f));
    gb[f] = ge * g;
  }
  __syncthreads();

  // ---- stage D: g2[o'] = sum_c w_before[o',c] * g[c];  o' = ob, ob+32 ----
  float acc3[2][8];
#pragma unroll
  for (int i = 0; i < 2; ++i)
#pragma unroll
    for (int j = 0; j < 8; ++j) acc3[i][j] = 0.f;

#pragma unroll 2
  for (int c = 0; c < 64; ++c) {
    float4 lo = *(const float4*)(gb + c * 64 + pb * 8);
    float4 hi = *(const float4*)(gb + c * 64 + pb * 8 + 4);
    float gv[8] = {lo.x, lo.y, lo.z, lo.w, hi.x, hi.y, hi.z, hi.w};
    float wv0 = w_before[ob * 64 + c];
    float wv1 = w_before[(ob + 32) * 64 + c];
#pragma unroll
    for (int j = 0; j < 8; ++j) {
      acc3[0][j] += wv0 * gv[j];
      acc3[1][j] += wv1 * gv[j];
    }
  }

  size_t obase = (size_t)b * 64 * PLANE + (size_t)(h0 + pb) * WW + w0;
#pragma unroll
  for (int i = 0; i < 2; ++i) {
    int o = ob + i * 32;
    float* dst = g2 + obase + (size_t)o * PLANE;
    *(float4*)dst = make_float4(acc3[i][0], acc3[i][1], acc3[i][2], acc3[i][3]);
    *(float4*)(dst + 4) =
        make_float4(acc3[i][4], acc3[i][5], acc3[i][6], acc3[i][7]);
  }
}

// ---------------------------------------------------------------------------
// Depthwise 3x3, SAME.  Block: 8 rows x 64 cols of one (b,c) plane.
// ---------------------------------------------------------------------------
__global__ __launch_bounds__(256) void dwconv_kernel(
    const float* __restrict__ g2, const float* __restrict__ w_dw,
    float* __restrict__ dout) {
  int wseg = blockIdx.x;  // 0..3
  int hseg = blockIdx.y;  // 0..31
  int bc = blockIdx.z;    // 0..511  (b*64 + c)
  int c = bc & 63;
  const float* src = g2 + (size_t)bc * PLANE;
  float* dst = dout + (size_t)bc * PLANE;
  __shared__ float tile[10][66];
  int w0 = wseg * 64, h0 = hseg * 8;
  int t = threadIdx.x;
  for (int f = t; f < 660; f += 256) {
    int r = f / 66, cl = f - r * 66;
    int hh = h0 + r - 1, ww = w0 + cl - 1;
    float v = 0.f;
    if (hh >= 0 && hh < HH && ww >= 0 && ww < WW) v = src[hh * WW + ww];
    tile[r][cl] = v;
  }
  float k9[9];
#pragma unroll
  for (int i = 0; i < 9; ++i) k9[i] = w_dw[c * 9 + i];
  __syncthreads();
#pragma unroll
  for (int rep = 0; rep < 2; ++rep) {
    int r = rep * 4 + (t >> 6);
    int cl = t & 63;
    float s = 0.f;
#pragma unroll
    for (int i = 0; i < 3; ++i)
#pragma unroll
      for (int j = 0; j < 3; ++j) s += k9[i * 3 + j] * tile[r + i][cl + j];
    dst[(size_t)(h0 + r) * WW + w0 + cl] = s;
  }
}

// ---------------------------------------------------------------------------
// out = w_out @ d + x.  Block: one 64-px row segment, all 128 out-channels.
// ---------------------------------------------------------------------------
__global__ __launch_bounds__(256) void mixout_kernel(
    const float* __restrict__ d, const float* __restrict__ w_out,
    const float* __restrict__ x, float* __restrict__ out) {
  int bid = blockIdx.x;  // 8192 = b*1024 + hh*4 + wseg
  int wseg = bid & 3;
  int hh = (bid >> 2) & 255;
  int b = bid >> 10;
  __shared__ float ds[64 * 64];
  int t = threadIdx.x;
  const float* dbase = d + (size_t)b * 64 * PLANE + (size_t)hh * WW + wseg * 64;
#pragma unroll
  for (int i = 0; i < 4; ++i) {
    int f = t + 256 * i;  // float4 id, 0..1023
    int c = f >> 4, k4 = f & 15;
    *(float4*)(ds + c * 64 + k4 * 4) =
        *(const float4*)(dbase + (size_t)c * PLANE + k4 * 4);
  }
  __syncthreads();
  int o2 = t >> 3, pb = t & 7;
  float acc[4][8];
#pragma unroll
  for (int i = 0; i < 4; ++i)
#pragma unroll
    for (int j = 0; j < 8; ++j) acc[i][j] = 0.f;

#pragma unroll 2
  for (int c = 0; c < 64; ++c) {
    float4 lo = *(const float4*)(ds + c * 64 + pb * 8);
    float4 hi = *(const float4*)(ds + c * 64 + pb * 8 + 4);
    float gv[8] = {lo.x, lo.y, lo.z, lo.w, hi.x, hi.y, hi.z, hi.w};
#pragma unroll
    for (int i = 0; i < 4; ++i) {
      float wv = w_out[(o2 + i * 32) * 64 + c];
#pragma unroll
      for (int j = 0; j < 8; ++j) acc[i][j] += wv * gv[j];
    }
  }

  size_t base =
      (size_t)b * CC * PLANE + (size_t)hh * WW + (size_t)wseg * 64 + pb * 8;
#pragma unroll
  for (int i = 0; i < 4; ++i) {
    int o = o2 + i * 32;
    const float* xp = x + base + (size_t)o * PLANE;
    float* op = out + base + (size_t)o * PLANE;
    float4 xlo = *(const float4*)xp;
    float4 xhi = *(const float4*)(xp + 4);
    float4 r0 = make_float4(acc[i][0] + xlo.x, acc[i][1] + xlo.y,
                            acc[i][2] + xlo.z, acc[i][3] + xlo.w);
    float4 r1 = make_float4(acc[i][4] + xhi.x, acc[i][5] + xhi.y,
                            acc[i][6] + xhi.z, acc[i][7] + xhi.w);
    *(float4*)op = r0;
    *(float4*)(op + 4) = r1;
  }
}

extern "C" void kernel_launch(void* const* d_in, const int* in_sizes, int n_in,
                              void* d_out, int out_size, void* d_ws,
                              size_t ws_size, hipStream_t stream) {
  const float* x = (const float*)d_in[0];
  const float* fft_filt = (const float*)d_in[1];
  const float* w_in = (const float*)d_in[2];
  const float* w_before = (const float*)d_in[3];
  const float* w_dw = (const float*)d_in[4];
  const float* w_out = (const float*)d_in[5];
  float* out = (float*)d_out;

  char* ws = (char*)d_ws;
  float* kk = (float*)ws;                     // 128*64 floats = 32 KB
  float* g2 = (float*)(ws + (1 << 16));       // 8*64*65536 floats = 128 MB
  float* dbuf = g2 + (size_t)BB * 64 * PLANE; // 128 MB

  hipLaunchKernelGGL(make_k_kernel, dim3(32), dim3(256), 0, stream, fft_filt,
                     kk);
  hipLaunchKernelGGL(fused1_kernel, dim3(8192), dim3(256), 0, stream, x, w_in,
                     w_before, kk, g2);
  hipLaunchKernelGGL(dwconv_kernel, dim3(4, 32, 512), dim3(256), 0, stream, g2,
                     w_dw, dbuf);
  hipLaunchKernelGGL(mixout_kernel, dim3(8192), dim3(256), 0, stream, dbuf,
                     w_out, x, out);
}

// Round 2
// 1217.307 us; speedup vs baseline: 1.0955x; 1.0955x over previous
//
#include <hip/hip_runtime.h>
#include <math.h>

#define BB 8
#define CC 128
#define HH 256
#define WW 256
#define PLANE (HH * WW)

// ---------------------------------------------------------------------------
// Prep: build (a) kkt[un*128+c] -- effective 8x8 circular-conv kernel of
// irfft2(rfft2(.)*filt), transposed so channel is fastest;  (b) w_in_t[c][o];
// (c) w_before_t[c][o];  (d) w_out_t[c][o].  All transposed so that the
// compute kernels read weights for consecutive output channels contiguously
// (dwordx4 vector loads / wide scalar loads) instead of per-lane scattered
// dword loads.
// ---------------------------------------------------------------------------
__global__ __launch_bounds__(256) void prep_kernel(
    const float* __restrict__ filt, const float* __restrict__ w_in,
    const float* __restrict__ w_before, const float* __restrict__ w_out,
    float* __restrict__ kkt, float* __restrict__ w_in_t,
    float* __restrict__ w_before_t, float* __restrict__ w_out_t) {
  int idx = blockIdx.x * 256 + threadIdx.x;
  if (idx < 8192) {
    // kkt: k_c[u,n] = (1/64) sum_{p,q} m_q filt[c,p,q] cos(2pi(pu+qn)/8)
    int c = idx >> 6;
    int un = idx & 63;
    int u = un >> 3, n = un & 7;
    const float cs8[8] = {1.f,  0.70710678118654752f,  0.f, -0.70710678118654752f,
                          -1.f, -0.70710678118654752f, 0.f, 0.70710678118654752f};
    float s = 0.f;
#pragma unroll
    for (int p = 0; p < 8; ++p) {
#pragma unroll
      for (int q = 0; q < 5; ++q) {
        float m = (q == 0 || q == 4) ? 1.f : 2.f;
        s += m * filt[(c * 8 + p) * 5 + q] * cs8[(p * u + q * n) & 7];
      }
    }
    kkt[un * 128 + c] = s * (1.f / 64.f);
  } else if (idx < 24576) {
    int j = idx - 8192;
    int o = j >> 7, c = j & 127;
    w_in_t[c * 128 + o] = w_in[o * 128 + c];
  } else if (idx < 28672) {
    int j = idx - 24576;
    int o = j >> 6, c = j & 63;
    w_before_t[c * 64 + o] = w_before[o * 64 + c];
  } else if (idx < 36864) {
    int j = idx - 28672;
    int o = j >> 6, c = j & 63;
    w_out_t[c * 128 + o] = w_out[o * 64 + c];
  }
}

// ---------------------------------------------------------------------------
// Fused: w_in mix -> per-channel 8x8 circular conv (rolling register
// shuffles) -> exact GeGLU (in-place in LDS) -> w_before mix.
// One block per 8x8 patch; thread (ob,pb) owns 4 out-channels x row pb.
// LDS: single 32 KB buffer (x patch, then y2, then gated g in low half).
// ---------------------------------------------------------------------------
__global__ __launch_bounds__(256) void fused1_kernel(
    const float* __restrict__ x, const float* __restrict__ w_in_t,
    const float* __restrict__ w_before_t, const float* __restrict__ kkt,
    float* __restrict__ g2) {
  __shared__ float buf[128 * 64];

  int bid = blockIdx.x;
  int b = bid >> 10;
  int py = (bid >> 5) & 31;
  int px = bid & 31;
  int h0 = py * 8, w0 = px * 8;
  int t = threadIdx.x;
  const float* xb = x + (size_t)b * CC * PLANE;

  // ---- load 128ch x 8x8 patch into LDS ----
#pragma unroll
  for (int i = 0; i < 8; ++i) {
    int f = t + 256 * i;  // float4 id
    int r = f >> 1;
    int k4 = f & 1;
    int c = r >> 3, ph = r & 7;
    float4 v = *(const float4*)(xb + (size_t)c * PLANE +
                                (size_t)(h0 + ph) * WW + w0 + k4 * 4);
    *(float4*)(buf + c * 64 + ph * 8 + k4 * 4) = v;
  }
  __syncthreads();

  int ob = t >> 3;  // 0..31: out-channels ob*4..ob*4+3
  int pb = t & 7;   // patch row

  // ---- stage A: y[o][pb][:] = sum_c w_in[o,c] * x[c][pb][:] ----
  float acc[4][8];
#pragma unroll
  for (int i = 0; i < 4; ++i)
#pragma unroll
    for (int j = 0; j < 8; ++j) acc[i][j] = 0.f;

  const float* wp = w_in_t + ob * 4;
  const float* bp = buf + pb * 8;
#pragma unroll 4
  for (int c = 0; c < 128; ++c) {
    float4 lo = *(const float4*)(bp + c * 64);
    float4 hi = *(const float4*)(bp + c * 64 + 4);
    float4 wv = *(const float4*)(wp + c * 128);
    float xv[8] = {lo.x, lo.y, lo.z, lo.w, hi.x, hi.y, hi.z, hi.w};
    float wa[4] = {wv.x, wv.y, wv.z, wv.w};
#pragma unroll
    for (int i = 0; i < 4; ++i)
#pragma unroll
      for (int j = 0; j < 8; ++j) acc[i][j] += wa[i] * xv[j];
  }

  // ---- stage B: 8x8 circular conv.  r holds y row (pb-s)&7; rolling shift
  // by one row per s via a single bpermute per register.  kkt gives the 4
  // kernel values for this thread's 4 channels in one dwordx4.
  float acc2[4][8];
#pragma unroll
  for (int i = 0; i < 4; ++i)
#pragma unroll
    for (int j = 0; j < 8; ++j) acc2[i][j] = 0.f;

  float r8[4][8];
#pragma unroll
  for (int i = 0; i < 4; ++i)
#pragma unroll
    for (int j = 0; j < 8; ++j) r8[i][j] = acc[i][j];

  const float* kb = kkt + ob * 4;
  int srcm1 = (t & 56) | ((t - 1) & 7);
#pragma unroll
  for (int s = 0; s < 8; ++s) {
    if (s > 0) {
#pragma unroll
      for (int i = 0; i < 4; ++i)
#pragma unroll
        for (int j = 0; j < 8; ++j) r8[i][j] = __shfl(r8[i][j], srcm1, 64);
    }
#pragma unroll
    for (int tt = 0; tt < 8; ++tt) {
      float4 kv = *(const float4*)(kb + (s * 8 + tt) * 128);
      float ka[4] = {kv.x, kv.y, kv.z, kv.w};
#pragma unroll
      for (int i = 0; i < 4; ++i)
#pragma unroll
        for (int j = 0; j < 8; ++j)
          acc2[i][j] += ka[i] * r8[i][(j - tt) & 7];
    }
  }
  __syncthreads();  // all stage-A reads of buf complete

  // ---- write y2 into buf ----
#pragma unroll
  for (int i = 0; i < 4; ++i) {
    float* dst = buf + (ob * 4 + i) * 64 + pb * 8;
    *(float4*)dst = make_float4(acc2[i][0], acc2[i][1], acc2[i][2], acc2[i][3]);
    *(float4*)(dst + 4) =
        make_float4(acc2[i][4], acc2[i][5], acc2[i][6], acc2[i][7]);
  }
  __syncthreads();

  // ---- stage C: g[c] = gelu_exact(y2[c]) * y2[c+64], in place (low half) ----
#pragma unroll
  for (int it = 0; it < 16; ++it) {
    int f = t + it * 256;  // c*64 + pix, c<64
    float a = buf[f];
    float g = buf[f + 4096];
    float ge = 0.5f * a * (1.f + erff(a * 0.70710678118654752f));
    buf[f] = ge * g;
  }
  __syncthreads();

  // ---- stage D: g2[o'] = sum_c w_before[o',c]*g[c]; o' = 2ob, 2ob+1 ----
  float acc3[2][8];
#pragma unroll
  for (int i = 0; i < 2; ++i)
#pragma unroll
    for (int j = 0; j < 8; ++j) acc3[i][j] = 0.f;

  const float* wbp = w_before_t + ob * 2;
#pragma unroll 4
  for (int c = 0; c < 64; ++c) {
    float4 lo = *(const float4*)(bp + c * 64);
    float4 hi = *(const float4*)(bp + c * 64 + 4);
    float2 wv = *(const float2*)(wbp + c * 64);
    float gv[8] = {lo.x, lo.y, lo.z, lo.w, hi.x, hi.y, hi.z, hi.w};
#pragma unroll
    for (int j = 0; j < 8; ++j) {
      acc3[0][j] += wv.x * gv[j];
      acc3[1][j] += wv.y * gv[j];
    }
  }

  size_t obase = (size_t)b * 64 * PLANE + (size_t)(h0 + pb) * WW + w0;
#pragma unroll
  for (int i = 0; i < 2; ++i) {
    int o = ob * 2 + i;
    float* dst = g2 + obase + (size_t)o * PLANE;
    *(float4*)dst = make_float4(acc3[i][0], acc3[i][1], acc3[i][2], acc3[i][3]);
    *(float4*)(dst + 4) =
        make_float4(acc3[i][4], acc3[i][5], acc3[i][6], acc3[i][7]);
  }
}

// ---------------------------------------------------------------------------
// Depthwise 3x3, SAME.  Block: 32 rows x 64 cols of one (b,c) plane;
// 8 output px per thread.
// ---------------------------------------------------------------------------
__global__ __launch_bounds__(256) void dwconv_kernel(
    const float* __restrict__ g2, const float* __restrict__ w_dw,
    float* __restrict__ dout) {
  int wseg = blockIdx.x;  // 0..3
  int hseg = blockIdx.y;  // 0..7
  int bc = blockIdx.z;    // 0..511
  int c = bc & 63;
  const float* src = g2 + (size_t)bc * PLANE;
  float* dst = dout + (size_t)bc * PLANE;
  __shared__ float tile[34][66];
  int w0 = wseg * 64, h0 = hseg * 32;
  int t = threadIdx.x;
  for (int f = t; f < 34 * 66; f += 256) {
    int r = f / 66, cl = f - r * 66;
    int hh = h0 + r - 1, ww = w0 + cl - 1;
    float v = 0.f;
    if (hh >= 0 && hh < HH && ww >= 0 && ww < WW) v = src[hh * WW + ww];
    tile[r][cl] = v;
  }
  float k9[9];
#pragma unroll
  for (int i = 0; i < 9; ++i) k9[i] = w_dw[c * 9 + i];
  __syncthreads();
  int cl = t & 63;
#pragma unroll
  for (int rep = 0; rep < 8; ++rep) {
    int r = rep * 4 + (t >> 6);
    float s = 0.f;
#pragma unroll
    for (int i = 0; i < 3; ++i)
#pragma unroll
      for (int j = 0; j < 3; ++j) s += k9[i * 3 + j] * tile[r + i][cl + j];
    dst[(size_t)(h0 + r) * WW + w0 + cl] = s;
  }
}

// ---------------------------------------------------------------------------
// out = w_out @ d + x.  Block: one 64-px row segment.  Lanes own pixels,
// weights are wave-uniform (scalar loads); each thread owns 32 out-channels.
// ---------------------------------------------------------------------------
__global__ __launch_bounds__(256) void mixout_kernel(
    const float* __restrict__ d, const float* __restrict__ w_out_t,
    const float* __restrict__ x, float* __restrict__ out) {
  int bid = blockIdx.x;  // b*1024 + hh*4 + wseg
  int wseg = bid & 3;
  int hh = (bid >> 2) & 255;
  int b = bid >> 10;
  __shared__ float ds[64 * 64];
  int t = threadIdx.x;
  const float* dbase = d + (size_t)b * 64 * PLANE + (size_t)hh * WW + wseg * 64;
#pragma unroll
  for (int i = 0; i < 4; ++i) {
    int f = t + 256 * i;  // float4 id
    int c = f >> 4, k4 = f & 15;
    *(float4*)(ds + c * 64 + k4 * 4) =
        *(const float4*)(dbase + (size_t)c * PLANE + k4 * 4);
  }
  __syncthreads();

  int og = __builtin_amdgcn_readfirstlane(t >> 6);  // wave-uniform
  int pix = t & 63;
  float acc[32];
#pragma unroll
  for (int i = 0; i < 32; ++i) acc[i] = 0.f;

  const float* wt = w_out_t + og * 32;
#pragma unroll 2
  for (int c = 0; c < 64; ++c) {
    float xv = ds[c * 64 + pix];
#pragma unroll
    for (int i = 0; i < 32; ++i) acc[i] += wt[c * 128 + i] * xv;
  }

  size_t pbase =
      (size_t)b * CC * PLANE + (size_t)hh * WW + (size_t)wseg * 64 + pix;
#pragma unroll
  for (int i = 0; i < 32; ++i) {
    int o = og * 32 + i;
    out[pbase + (size_t)o * PLANE] = acc[i] + x[pbase + (size_t)o * PLANE];
  }
}

extern "C" void kernel_launch(void* const* d_in, const int* in_sizes, int n_in,
                              void* d_out, int out_size, void* d_ws,
                              size_t ws_size, hipStream_t stream) {
  const float* x = (const float*)d_in[0];
  const float* fft_filt = (const float*)d_in[1];
  const float* w_in = (const float*)d_in[2];
  const float* w_before = (const float*)d_in[3];
  const float* w_dw = (const float*)d_in[4];
  const float* w_out = (const float*)d_in[5];
  float* out = (float*)d_out;

  char* ws = (char*)d_ws;
  float* kkt = (float*)ws;                    // 8192 floats
  float* w_in_t = kkt + 8192;                 // 16384 floats
  float* w_before_t = w_in_t + 16384;         // 4096 floats
  float* w_out_t = w_before_t + 4096;         // 8192 floats
  float* g2 = (float*)(ws + (1 << 20));       // 128 MB
  float* dbuf = g2 + (size_t)BB * 64 * PLANE; // 128 MB

  hipLaunchKernelGGL(prep_kernel, dim3(144), dim3(256), 0, stream, fft_filt,
                     w_in, w_before, w_out, kkt, w_in_t, w_before_t, w_out_t);
  hipLaunchKernelGGL(fused1_kernel, dim3(8192), dim3(256), 0, stream, x,
                     w_in_t, w_before_t, kkt, g2);
  hipLaunchKernelGGL(dwconv_kernel, dim3(4, 8, 512), dim3(256), 0, stream, g2,
                     w_dw, dbuf);
  hipLaunchKernelGGL(mixout_kernel, dim3(8192), dim3(256), 0, stream, dbuf,
                     w_out_t, x, out);
}